// Round 3
// baseline (726.575 us; speedup 1.0000x reference)
//
#include <hip/hip_runtime.h>
#include <stdint.h>

#define D   64
#define L   50
#define NUM_U 30000
#define NUM_I 20000

__device__ __forceinline__ float bf2f(unsigned short u) {
    union { unsigned int i; float f; } v; v.i = ((unsigned int)u) << 16; return v.f;
}
__device__ __forceinline__ float lof(unsigned int u) {
    union { unsigned int i; float f; } v; v.i = u << 16; return v.f;
}
__device__ __forceinline__ float hif(unsigned int u) {
    union { unsigned int i; float f; } v; v.i = u & 0xffff0000u; return v.f;
}
__device__ __forceinline__ unsigned short f2bf(float f) {
    union { float f; unsigned int i; } v; v.f = f;
    unsigned int x = v.i;
    return (unsigned short)((x + 0x7fffu + ((x >> 16) & 1u)) >> 16);
}

// Detect float-tensor dtype from W_u's first 64 dwords (in-bounds either way:
// W_u is >= 8 KB as bf16, >= 16 KB as f32).
// Packed bf16: bits 14..7 of each dword = low element's exponent, concentrated
// near 122 for 0.05*N(0,1) data  -> ~64/64 in band.
// Raw f32: bits 14..7 are mantissa bits, uniform                -> ~9/64 in band.
// (bf16-rounded values stored in f32 buffers give low16=0 -> f32 verdict: correct.)
// flag: 0 = bf16 buffers, 1 = f32 buffers.
__global__ void detect_dtype(const unsigned int* __restrict__ w,
                             int* __restrict__ flag)
{
    int lane = threadIdx.x;
    unsigned int b = (w[lane] >> 7) & 0xffu;
    int band = (b >= 104u && b <= 140u) ? 1 : 0;
    unsigned long long m = __ballot(band);
    if (lane == 0) flag[0] = (__popcll(m) >= 40) ? 0 : 1;
}

// One wave per destination node. Fused DGSR reduce; algebraic refactor:
//   dh = W_dst^T f_dst ; e_l = raw_l . (W_src dh) + te[re_o_l].dh
//   e1_l = raw_l . (W_src W_src^T raw_last)
//   h_long = W_src^T (sum a raw_l) + sum a te_k[re_o_l] ; h_short = W_src^T (sum a1 raw_l)
template<int F32, int WAVES>
__global__ __launch_bounds__(256) void attn_fused(
    const int* __restrict__ flag,
    const void* __restrict__ src_feat_v,
    const void* __restrict__ dst_feat_v,
    const void* __restrict__ W_src_v,
    const void* __restrict__ W_dst_v,
    const void* __restrict__ Wg_v,
    const void* __restrict__ te_v,
    const void* __restrict__ tek_v,
    const int* __restrict__ nbr,
    const int* __restrict__ timev,
    void* __restrict__ out_v,
    long out_off)                       // element offset into out
{
    if (flag[0] != F32) return;         // block-uniform predicate

    constexpr int WS_DW = F32 ? 64 * 65 : 64 * 33;   // W_src staging
    constexpr int WG_DW = F32 ? 0       : 64 * 64;   // packed Wg (bf16 path only)
    constexpr int MB_DW = F32 ? L * 65  : L * 33;    // per-wave mailbox
    __shared__ unsigned int smem[WS_DW + WG_DW + WAVES * MB_DW];

    const int tid = threadIdx.x, lane = tid & 63, wid = tid >> 6;
    const int n = blockIdx.x * WAVES + wid;
    constexpr int NT = WAVES * 64;

    // ---- cooperative weight staging ----
    if constexpr (F32) {
        float* wsf = (float*)smem;                       // 64 x 65 (stride kills conflicts)
        const float* W = (const float*)W_src_v;
        for (int idx = tid; idx < 4096; idx += NT)
            wsf[(idx >> 6) * 65 + (idx & 63)] = W[idx];
    } else {
        unsigned int* ws32 = smem;                       // 64 rows x 33 dwords
        unsigned int* wg32 = smem + WS_DW;               // packed (Wg[k][d], Wg[k+64][d])
        const unsigned int* w = (const unsigned int*)W_src_v;
        for (int idx = tid; idx < 2048; idx += NT)
            ws32[(idx >> 5) * 33 + (idx & 31)] = w[idx];
        const unsigned short* g = (const unsigned short*)Wg_v;
        for (int idx = tid; idx < 4096; idx += NT)
            wg32[idx] = (unsigned int)g[idx] | ((unsigned int)g[idx + 4096] << 16);
    }
    __syncthreads();

    // ---- neighborhood metadata (dtype-independent) ----
    int t  = (lane < L) ? timev[(size_t)n * L + lane] : 0;
    int nb = (lane < L) ? nbr[(size_t)n * L + lane]  : 0;
    unsigned int key  = (lane < L) ? ((((unsigned)t) << 6) | (unsigned)lane) : 0u;
    unsigned int key2 = (lane < L) ? ((((unsigned)t) << 6) | (unsigned)(63 - lane)) : 0u;

    int rank = 0;                        // stable ascending rank = argsort(argsort)
#pragma unroll
    for (int j = 0; j < L; j++) rank += (__shfl(key, j) < key) ? 1 : 0;
    int re_o = (lane < L) ? (L - 1 - rank) : 0;

    unsigned int m2 = key2;              // first argmax(time)
#pragma unroll
    for (int s = 32; s; s >>= 1) { unsigned int o = __shfl_xor(m2, s); m2 = (o > m2) ? o : m2; }
    int last = 63 - (int)(m2 & 63u);

    const int rr    = (lane < L) ? lane : (L - 1);
    const int myrow = rr;

    float f, dh = 0.f, v1 = 0.f, v2 = 0.f, teh = 0.f, e = 0.f, e1 = 0.f;

    if constexpr (F32) {
        const float* srcf = (const float*)src_feat_v;
        const float* dstf = (const float*)dst_feat_v;
        const float* Wd   = (const float*)W_dst_v;
        const float* tef  = (const float*)te_v;
        float* wsf = (float*)smem;
        float* mbf = (float*)(smem + WS_DW) + wid * MB_DW;

        f = dstf[(size_t)n * D + lane];
#pragma unroll
        for (int k = 0; k < 64; k++)
            dh += __shfl(f, k) * Wd[k * 64 + lane];           // coalesced, L1
#pragma unroll
        for (int d = 0; d < 64; d++)
            v1 += __shfl(dh, d) * wsf[lane * 65 + d];
#pragma unroll
        for (int l = 0; l < L; l++) {
            int nbl = __shfl(nb, l);
            mbf[l * 65 + lane] = srcf[(size_t)nbl * D + lane];
        }
        __syncthreads();
        float rlast = mbf[last * 65 + lane];
        float g = 0.f;
#pragma unroll
        for (int k = 0; k < 64; k++)
            g += __shfl(rlast, k) * wsf[k * 65 + lane];
#pragma unroll
        for (int d = 0; d < 64; d++)
            v2 += __shfl(g, d) * wsf[lane * 65 + d];
#pragma unroll
        for (int d = 0; d < 64; d++)
            teh += tef[rr * 64 + d] * __shfl(dh, d);
#pragma unroll
        for (int j = 0; j < 64; j++) {
            float m = mbf[myrow * 65 + j];
            e  += m * __shfl(v1, j);
            e1 += m * __shfl(v2, j);
        }
    } else {
        const unsigned short* srcf = (const unsigned short*)src_feat_v;
        const unsigned short* dstf = (const unsigned short*)dst_feat_v;
        const unsigned short* Wd   = (const unsigned short*)W_dst_v;
        const unsigned int* te32   = (const unsigned int*)te_v;
        unsigned int* ws32  = smem;
        unsigned short* w16 = (unsigned short*)smem;
        unsigned short* mb16 = (unsigned short*)(smem + WS_DW + WG_DW) + wid * (MB_DW * 2);
        const unsigned int* mbw = smem + WS_DW + WG_DW + wid * MB_DW;

        f = bf2f(dstf[(size_t)n * D + lane]);
#pragma unroll
        for (int k = 0; k < 64; k++)
            dh += __shfl(f, k) * bf2f(Wd[k * 64 + lane]);
#pragma unroll
        for (int j = 0; j < 32; j++) {
            unsigned int u = ws32[lane * 33 + j];
            v1 += lof(u) * __shfl(dh, 2 * j) + hif(u) * __shfl(dh, 2 * j + 1);
        }
#pragma unroll
        for (int l = 0; l < L; l++) {
            int nbl = __shfl(nb, l);
            mb16[l * 66 + lane] = srcf[(size_t)nbl * D + lane];
        }
        __syncthreads();
        float rlast = bf2f(mb16[last * 66 + lane]);
        float g = 0.f;
#pragma unroll
        for (int k = 0; k < 64; k++)
            g += __shfl(rlast, k) * bf2f(w16[k * 66 + lane]);
#pragma unroll
        for (int j = 0; j < 32; j++) {
            unsigned int u = ws32[lane * 33 + j];
            v2 += lof(u) * __shfl(g, 2 * j) + hif(u) * __shfl(g, 2 * j + 1);
        }
#pragma unroll
        for (int dw = 0; dw < 32; dw++) {
            unsigned int u = te32[rr * 32 + dw];
            teh += lof(u) * __shfl(dh, 2 * dw) + hif(u) * __shfl(dh, 2 * dw + 1);
        }
#pragma unroll
        for (int j = 0; j < 32; j++) {
            unsigned int u = mbw[myrow * 33 + j];
            float m0 = lof(u), m1 = hif(u);
            e  += m0 * __shfl(v1, 2 * j) + m1 * __shfl(v1, 2 * j + 1);
            e1 += m0 * __shfl(v2, 2 * j) + m1 * __shfl(v2, 2 * j + 1);
        }
    }

    // ---- shared: scores -> dual softmax over neighbors ----
    e = (e + __shfl(teh, re_o)) * 0.125f;
    e1 *= 0.125f;
    if (lane >= L) { e = -3e38f; e1 = -3e38f; }   // finite sentinel (fast-math safe)

    float mx = e;
#pragma unroll
    for (int s = 32; s; s >>= 1) { float o = __shfl_xor(mx, s); mx = (o > mx) ? o : mx; }
    float ex = __expf(e - mx);
    float sm = ex;
#pragma unroll
    for (int s = 32; s; s >>= 1) sm += __shfl_xor(sm, s);
    float alpha = ex / sm;

    float mx1 = e1;
#pragma unroll
    for (int s = 32; s; s >>= 1) { float o = __shfl_xor(mx1, s); mx1 = (o > mx1) ? o : mx1; }
    float ex1 = __expf(e1 - mx1);
    float sm1 = ex1;
#pragma unroll
    for (int s = 32; s; s >>= 1) sm1 += __shfl_xor(sm1, s);
    float a1 = ex1 / sm1;

    // ---- epilogue: weighted sums, W_src^T, Wg projection, residual ELU ----
    float sl = 0.f, ss = 0.f, tacc = 0.f;
    if constexpr (F32) {
        const float* tkf = (const float*)tek_v;
        float* wsf = (float*)smem;
        float* mbf = (float*)(smem + WS_DW) + wid * MB_DW;
#pragma unroll
        for (int l = 0; l < L; l++) {
            float sa = __shfl(alpha, l), s1 = __shfl(a1, l);
            int ro = __shfl(re_o, l);
            float m = mbf[l * 65 + lane];
            sl += sa * m; ss += s1 * m;
            tacc += sa * tkf[ro * 64 + lane];
        }
        float hl = tacc, hs = 0.f;
#pragma unroll
        for (int k = 0; k < 64; k++) {
            float w = wsf[k * 65 + lane];
            hl += __shfl(sl, k) * w;
            hs += __shfl(ss, k) * w;
        }
        const float* Wgf = (const float*)Wg_v;
        float o = f;
#pragma unroll
        for (int k = 0; k < 64; k++)
            o += __shfl(hl, k) * Wgf[k * 64 + lane] + __shfl(hs, k) * Wgf[(k + 64) * 64 + lane];
        o = (o > 0.f) ? o : (__expf(o) - 1.f);
        ((float*)out_v)[out_off + (size_t)n * D + lane] = o;
    } else {
        const unsigned short* tk16 = (const unsigned short*)tek_v;
        unsigned short* w16 = (unsigned short*)smem;
        unsigned int* wg32 = smem + WS_DW;
        unsigned short* mb16 = (unsigned short*)(smem + WS_DW + WG_DW) + wid * (MB_DW * 2);
#pragma unroll
        for (int l = 0; l < L; l++) {
            float sa = __shfl(alpha, l), s1 = __shfl(a1, l);
            int ro = __shfl(re_o, l);
            float m = bf2f(mb16[l * 66 + lane]);
            sl += sa * m; ss += s1 * m;
            tacc += sa * bf2f(tk16[ro * 64 + lane]);
        }
        float hl = tacc, hs = 0.f;
#pragma unroll
        for (int k = 0; k < 64; k++) {
            float w = bf2f(w16[k * 66 + lane]);
            hl += __shfl(sl, k) * w;
            hs += __shfl(ss, k) * w;
        }
        float o = f;
#pragma unroll
        for (int k = 0; k < 64; k++) {
            unsigned int u = wg32[k * 64 + lane];
            o += __shfl(hl, k) * lof(u) + __shfl(hs, k) * hif(u);
        }
        o = (o > 0.f) ? o : (__expf(o) - 1.f);
        ((unsigned short*)out_v)[out_off + (size_t)n * D + lane] = f2bf(o);
    }
}

extern "C" void kernel_launch(void* const* d_in, const int* in_sizes, int n_in,
                              void* d_out, int out_size, void* d_ws, size_t ws_size,
                              hipStream_t stream) {
    const void* user_feat = d_in[0];
    const void* item_feat = d_in[1];
    const void* W_u  = d_in[2];
    const void* W_i  = d_in[3];
    const void* Wg_u = d_in[4];
    const void* Wg_i = d_in[5];
    const void* i_te   = d_in[6];
    const void* i_te_k = d_in[7];
    const void* u_te   = d_in[8];
    const void* u_te_k = d_in[9];
    const int* item_nbr  = (const int*)d_in[10];
    const int* item_time = (const int*)d_in[11];
    const int* user_nbr  = (const int*)d_in[12];
    const int* user_time = (const int*)d_in[13];
    (void)in_sizes; (void)n_in; (void)out_size; (void)ws_size;

    int* flag = (int*)d_ws;
    detect_dtype<<<1, 64, 0, stream>>>((const unsigned int*)W_u, flag);

    // item side: mailbox = user rows (W_u), dst = items (W_i); out offset NUM_U*D
    attn_fused<0, 4><<<NUM_I / 4, 256, 0, stream>>>(
        flag, user_feat, item_feat, W_u, W_i, Wg_i, i_te, i_te_k,
        item_nbr, item_time, d_out, (long)NUM_U * D);
    attn_fused<1, 2><<<NUM_I / 2, 128, 0, stream>>>(
        flag, user_feat, item_feat, W_u, W_i, Wg_i, i_te, i_te_k,
        item_nbr, item_time, d_out, (long)NUM_U * D);

    // user side: mailbox = item rows (W_i), dst = users (W_u); out offset 0
    attn_fused<0, 4><<<NUM_U / 4, 256, 0, stream>>>(
        flag, item_feat, user_feat, W_i, W_u, Wg_u, u_te, u_te_k,
        user_nbr, user_time, d_out, 0L);
    attn_fused<1, 2><<<NUM_U / 2, 128, 0, stream>>>(
        flag, item_feat, user_feat, W_i, W_u, Wg_u, u_te, u_te_k,
        user_nbr, user_time, d_out, 0L);
}

// Round 4
// 656.800 us; speedup vs baseline: 1.1062x; 1.1062x over previous
//
#include <hip/hip_runtime.h>
#include <stdint.h>

#define D   64
#define L   50
#define NUM_U 30000
#define NUM_I 20000

// measured round 3: float tensors are f32 (f32 template path was the active one,
// passed absmax 0.0156). bf16 path + dtype detector removed.

__device__ __forceinline__ float lof(unsigned int u) {
    union { unsigned int i; float f; } v; v.i = u << 16; return v.f;
}
__device__ __forceinline__ float hif(unsigned int u) {
    union { unsigned int i; float f; } v; v.i = u & 0xffff0000u; return v.f;
}
__device__ __forceinline__ unsigned int f2bfbits(float f) {
    union { float f; unsigned int i; } v; v.f = f;
    return (v.i + 0x7fffu + ((v.i >> 16) & 1u)) >> 16;   // RNE
}
__device__ __forceinline__ unsigned int packbf(float a, float b) {
    return f2bfbits(a) | (f2bfbits(b) << 16);
}

// One wave per destination node, lanes = dim/neighbor as needed.
// Algebraic refactor (verified round 3):
//   dh = W_dst^T f_dst ; e_l = raw_l.(W_src dh) + te[re_o_l].dh
//   e1_l = raw_l.(W_src W_src^T raw_last)
//   h_long = W_src^T (sum a raw_l) + sum a te_k[re_o_l]; h_short = W_src^T (sum a1 raw_l)
// LDS: W_src, te, mailbox as packed-bf16 pairs, row stride 33 dwords
// (33 ≡ 1 mod 32 -> worst aliasing 2-way, which is free on CDNA4).
// 41.4 KB/block, 4 waves/block -> 3 blocks/CU = 12 waves/CU (37.5% occ).
__global__ __launch_bounds__(256) void attn_f32(
    const float* __restrict__ src_feat,   // [Nsrc,64]
    const float* __restrict__ dst_feat,   // [N,64]
    const float* __restrict__ W_src,      // [64,64]
    const float* __restrict__ W_dst,      // [64,64]
    const float* __restrict__ Wg,         // [128,64]
    const float* __restrict__ te,         // [50,64]
    const float* __restrict__ tek,        // [50,64]
    const int* __restrict__ nbr,          // [N,50]
    const int* __restrict__ timev,        // [N,50]
    float* __restrict__ out)              // [N,64]
{
    __shared__ unsigned int ws32[64 * 33];
    __shared__ unsigned int te32[L * 33];
    __shared__ unsigned int mbs[4][L * 33];

    const int tid = threadIdx.x, lane = tid & 63, wid = tid >> 6;
    const int n = blockIdx.x * 4 + wid;

    // ---- stage W_src (2048 f32-pairs) and te (1600 pairs) as packed bf16 ----
    {
        const float2* Wf2 = (const float2*)W_src;
        const float2* Te2 = (const float2*)te;
        for (int idx = tid; idx < 2048; idx += 256) {
            float2 w = Wf2[idx];
            ws32[(idx >> 5) * 33 + (idx & 31)] = packbf(w.x, w.y);
            if (idx < 1600) {
                float2 t2 = Te2[idx];
                te32[(idx >> 5) * 33 + (idx & 31)] = packbf(t2.x, t2.y);
            }
        }
    }
    __syncthreads();

    // ---- neighborhood metadata ----
    int t  = (lane < L) ? timev[(size_t)n * L + lane] : 0;
    int nb = (lane < L) ? nbr[(size_t)n * L + lane]  : 0;
    unsigned int key  = (lane < L) ? ((((unsigned)t) << 6) | (unsigned)lane) : 0u;
    unsigned int key2 = (lane < L) ? ((((unsigned)t) << 6) | (unsigned)(63 - lane)) : 0u;

    int rank = 0;                       // stable ascending rank = argsort(argsort)
#pragma unroll
    for (int j = 0; j < L; j++) rank += (__shfl(key, j) < key) ? 1 : 0;
    int re_o = (lane < L) ? (L - 1 - rank) : 0;

    unsigned int m2 = key2;             // first argmax(time)
#pragma unroll
    for (int s = 32; s; s >>= 1) { unsigned int o2 = __shfl_xor(m2, s); m2 = (o2 > m2) ? o2 : m2; }
    const int last = 63 - (int)(m2 & 63u);
    const int rr = (lane < L) ? lane : (L - 1);

    // ---- dh = W_dst^T f  (lanes = d), 4-way ILP, coalesced L1 reads ----
    float f = dst_feat[(size_t)n * D + lane];
    float dh;
    {
        float b0 = 0.f, b1 = 0.f, b2 = 0.f, b3 = 0.f;
#pragma unroll
        for (int k = 0; k < 64; k += 4) {
            b0 += __shfl(f, k + 0) * W_dst[(k + 0) * 64 + lane];
            b1 += __shfl(f, k + 1) * W_dst[(k + 1) * 64 + lane];
            b2 += __shfl(f, k + 2) * W_dst[(k + 2) * 64 + lane];
            b3 += __shfl(f, k + 3) * W_dst[(k + 3) * 64 + lane];
        }
        dh = (b0 + b1) + (b2 + b3);
    }

    // ---- v1 = W_src dh  (lanes = k), packed rows from LDS ----
    float v1;
    {
        float b0 = 0.f, b1 = 0.f, b2 = 0.f, b3 = 0.f;
#pragma unroll
        for (int j = 0; j < 32; j += 2) {
            unsigned int u0 = ws32[lane * 33 + j];
            unsigned int u1 = ws32[lane * 33 + j + 1];
            b0 += lof(u0) * __shfl(dh, 2 * j + 0);
            b1 += hif(u0) * __shfl(dh, 2 * j + 1);
            b2 += lof(u1) * __shfl(dh, 2 * j + 2);
            b3 += hif(u1) * __shfl(dh, 2 * j + 3);
        }
        v1 = (b0 + b1) + (b2 + b3);
    }

    // ---- gather mailbox (2 rows/iter: half-wave per row), bf16-pack ----
    unsigned int* mbw = mbs[wid];
    {
        const float2* src2 = (const float2*)src_feat;
        int half = lane >> 5, col = lane & 31;
#pragma unroll
        for (int l = 0; l < L; l += 2) {
            int ra = __shfl(nb, l), rb = __shfl(nb, l + 1);
            int r = half ? rb : ra;
            float2 v = src2[(size_t)r * 32 + col];
            mbw[(l + half) * 33 + col] = packbf(v.x, v.y);
        }
    }
    __syncthreads();

    // ---- raw_last (lanes = d) ----
    unsigned int ul = mbw[last * 33 + (lane >> 1)];
    float rlast = (lane & 1) ? hif(ul) : lof(ul);

    // ---- g = W_src^T raw_last  (lanes = d), f32 W from global (coalesced) ----
    float g;
    {
        float b0 = 0.f, b1 = 0.f, b2 = 0.f, b3 = 0.f;
#pragma unroll
        for (int k = 0; k < 64; k += 4) {
            b0 += __shfl(rlast, k + 0) * W_src[(k + 0) * 64 + lane];
            b1 += __shfl(rlast, k + 1) * W_src[(k + 1) * 64 + lane];
            b2 += __shfl(rlast, k + 2) * W_src[(k + 2) * 64 + lane];
            b3 += __shfl(rlast, k + 3) * W_src[(k + 3) * 64 + lane];
        }
        g = (b0 + b1) + (b2 + b3);
    }

    // ---- v2 = W_src g  (lanes = k) ----
    float v2;
    {
        float b0 = 0.f, b1 = 0.f, b2 = 0.f, b3 = 0.f;
#pragma unroll
        for (int j = 0; j < 32; j += 2) {
            unsigned int u0 = ws32[lane * 33 + j];
            unsigned int u1 = ws32[lane * 33 + j + 1];
            b0 += lof(u0) * __shfl(g, 2 * j + 0);
            b1 += hif(u0) * __shfl(g, 2 * j + 1);
            b2 += lof(u1) * __shfl(g, 2 * j + 2);
            b3 += hif(u1) * __shfl(g, 2 * j + 3);
        }
        v2 = (b0 + b1) + (b2 + b3);
    }

    // ---- teh[r] = te[r].dh  (lanes = rank), te from LDS ----
    float teh;
    {
        float b0 = 0.f, b1 = 0.f, b2 = 0.f, b3 = 0.f;
#pragma unroll
        for (int j = 0; j < 32; j += 2) {
            unsigned int u0 = te32[rr * 33 + j];
            unsigned int u1 = te32[rr * 33 + j + 1];
            b0 += lof(u0) * __shfl(dh, 2 * j + 0);
            b1 += hif(u0) * __shfl(dh, 2 * j + 1);
            b2 += lof(u1) * __shfl(dh, 2 * j + 2);
            b3 += hif(u1) * __shfl(dh, 2 * j + 3);
        }
        teh = (b0 + b1) + (b2 + b3);
    }

    // ---- scores e, e1  (lanes = neighbor) ----
    float e, e1;
    {
        float ea = 0.f, eb = 0.f, qa = 0.f, qb = 0.f;
#pragma unroll
        for (int j = 0; j < 32; j += 2) {
            unsigned int u0 = mbw[rr * 33 + j];
            unsigned int u1 = mbw[rr * 33 + j + 1];
            float m0 = lof(u0), m1 = hif(u0), m2f = lof(u1), m3 = hif(u1);
            ea += m0 * __shfl(v1, 2 * j + 0) + m1 * __shfl(v1, 2 * j + 1);
            eb += m2f * __shfl(v1, 2 * j + 2) + m3 * __shfl(v1, 2 * j + 3);
            qa += m0 * __shfl(v2, 2 * j + 0) + m1 * __shfl(v2, 2 * j + 1);
            qb += m2f * __shfl(v2, 2 * j + 2) + m3 * __shfl(v2, 2 * j + 3);
        }
        e = ea + eb; e1 = qa + qb;
    }
    e = (e + __shfl(teh, re_o)) * 0.125f;
    e1 *= 0.125f;
    if (lane >= L) { e = -3e38f; e1 = -3e38f; }

    // ---- dual softmax over neighbors ----
    float mx = e;
#pragma unroll
    for (int s = 32; s; s >>= 1) { float o2 = __shfl_xor(mx, s); mx = (o2 > mx) ? o2 : mx; }
    float ex = __expf(e - mx);
    float sm = ex;
#pragma unroll
    for (int s = 32; s; s >>= 1) sm += __shfl_xor(sm, s);
    float alpha = ex / sm;

    float mx1 = e1;
#pragma unroll
    for (int s = 32; s; s >>= 1) { float o2 = __shfl_xor(mx1, s); mx1 = (o2 > mx1) ? o2 : mx1; }
    float ex1 = __expf(e1 - mx1);
    float sm1 = ex1;
#pragma unroll
    for (int s = 32; s; s >>= 1) sm1 += __shfl_xor(sm1, s);
    float aw = ex1 / sm1;

    // ---- weighted sums over rows (lanes = d), tek from global (coalesced) ----
    float sl, ss, tacc;
    {
        float sA = 0.f, sB = 0.f, hA = 0.f, hB = 0.f, tA = 0.f, tB = 0.f;
        int hcol = lane >> 1, odd = lane & 1;
#pragma unroll
        for (int l = 0; l < L; l += 2) {
            float saA = __shfl(alpha, l),     s1A = __shfl(aw, l);
            float saB = __shfl(alpha, l + 1), s1B = __shfl(aw, l + 1);
            int   roA = __shfl(re_o, l),      roB = __shfl(re_o, l + 1);
            unsigned int uA = mbw[(l + 0) * 33 + hcol];
            unsigned int uB = mbw[(l + 1) * 33 + hcol];
            float mA = odd ? hif(uA) : lof(uA);
            float mB = odd ? hif(uB) : lof(uB);
            sA += saA * mA; hA += s1A * mA; tA += saA * tek[roA * 64 + lane];
            sB += saB * mB; hB += s1B * mB; tB += saB * tek[roB * 64 + lane];
        }
        sl = sA + sB; ss = hA + hB; tacc = tA + tB;
    }

    // ---- hl/hs = W_src^T sl/ss  (lanes = d), f32 W from global ----
    float hl, hs;
    {
        float lA = 0.f, lB = 0.f, sA = 0.f, sB = 0.f;
#pragma unroll
        for (int k = 0; k < 64; k += 2) {
            float w0 = W_src[(k + 0) * 64 + lane];
            float w1 = W_src[(k + 1) * 64 + lane];
            lA += __shfl(sl, k + 0) * w0; sA += __shfl(ss, k + 0) * w0;
            lB += __shfl(sl, k + 1) * w1; sB += __shfl(ss, k + 1) * w1;
        }
        hl = tacc + lA + lB; hs = sA + sB;
    }

    // ---- out = elu([hl|hs] @ Wg + f) ----
    float o;
    {
        float o0 = 0.f, o1 = 0.f, o2 = 0.f, o3 = 0.f;
#pragma unroll
        for (int k = 0; k < 64; k += 2) {
            o0 += __shfl(hl, k + 0) * Wg[(k + 0) * 64 + lane];
            o1 += __shfl(hl, k + 1) * Wg[(k + 1) * 64 + lane];
            o2 += __shfl(hs, k + 0) * Wg[(k + 64) * 64 + lane];
            o3 += __shfl(hs, k + 1) * Wg[(k + 65) * 64 + lane];
        }
        o = f + (o0 + o1) + (o2 + o3);
    }
    o = (o > 0.f) ? o : (__expf(o) - 1.f);
    out[(size_t)n * D + lane] = o;
}

extern "C" void kernel_launch(void* const* d_in, const int* in_sizes, int n_in,
                              void* d_out, int out_size, void* d_ws, size_t ws_size,
                              hipStream_t stream) {
    const float* user_feat = (const float*)d_in[0];
    const float* item_feat = (const float*)d_in[1];
    const float* W_u  = (const float*)d_in[2];
    const float* W_i  = (const float*)d_in[3];
    const float* Wg_u = (const float*)d_in[4];
    const float* Wg_i = (const float*)d_in[5];
    const float* i_te   = (const float*)d_in[6];
    const float* i_te_k = (const float*)d_in[7];
    const float* u_te   = (const float*)d_in[8];
    const float* u_te_k = (const float*)d_in[9];
    const int* item_nbr  = (const int*)d_in[10];
    const int* item_time = (const int*)d_in[11];
    const int* user_nbr  = (const int*)d_in[12];
    const int* user_time = (const int*)d_in[13];
    (void)in_sizes; (void)n_in; (void)out_size; (void)d_ws; (void)ws_size;

    float* outp = (float*)d_out;   // user_out then item_out

    // item side: mailbox = user rows (W_u), dst = items (W_i)
    attn_f32<<<NUM_I / 4, 256, 0, stream>>>(
        user_feat, item_feat, W_u, W_i, Wg_i, i_te, i_te_k,
        item_nbr, item_time, outp + (size_t)NUM_U * D);
    // user side: mailbox = item rows (W_i), dst = users (W_u)
    attn_f32<<<NUM_U / 4, 256, 0, stream>>>(
        item_feat, user_feat, W_i, W_u, Wg_u, u_te, u_te_k,
        user_nbr, user_time, outp);
}

// Round 5
// 447.259 us; speedup vs baseline: 1.6245x; 1.4685x over previous
//
#include <hip/hip_runtime.h>
#include <stdint.h>

#define D   64
#define L   50
#define NUM_U 30000
#define NUM_I 20000

// Round-3 measured: float tensors are f32. Round-4 measured: __shfl broadcasts
// lower to ds_bpermute (LDS pipe) and their data-dependent latency was the
// bottleneck (VALUBusy 25%). This round: wave-uniform broadcasts via
// v_readlane -> SGPR, consumed as the scalar operand of v_fmac (VALU pipe).

__device__ __forceinline__ float lof(unsigned int u) {
    union { unsigned int i; float f; } v; v.i = u << 16; return v.f;
}
__device__ __forceinline__ float hif(unsigned int u) {
    union { unsigned int i; float f; } v; v.i = u & 0xffff0000u; return v.f;
}
__device__ __forceinline__ unsigned int f2bfbits(float f) {
    union { float f; unsigned int i; } v; v.f = f;
    return (v.i + 0x7fffu + ((v.i >> 16) & 1u)) >> 16;   // RNE
}
__device__ __forceinline__ unsigned int packbf(float a, float b) {
    return f2bfbits(a) | (f2bfbits(b) << 16);
}
// wave-uniform broadcast: lane value -> SGPR (VALU pipe, no ds_bpermute)
__device__ __forceinline__ float rl(float v, int l) {
    return __int_as_float(__builtin_amdgcn_readlane(__float_as_int(v), l));
}
__device__ __forceinline__ int rli(int v, int l) {
    return __builtin_amdgcn_readlane(v, l);
}

// One wave per destination node. Algebra (verified round 3/4, absmax 0.0156):
//   dh = W_dst^T f ; e_l = raw_l.(W_src dh) + te[re_o_l].dh
//   e1_l = raw_l.(W_src W_src^T raw_last)
//   h_long = W_src^T (sum a raw_l) + sum a te_k[re_o_l]; h_short = W_src^T (sum a1 raw_l)
// LDS: W_src, te, mailbox packed bf16 pairs, row stride 33 dwords (2-way alias max).
__global__ __launch_bounds__(256) void attn_f32(
    const float* __restrict__ src_feat,   // [Nsrc,64]
    const float* __restrict__ dst_feat,   // [N,64]
    const float* __restrict__ W_src,      // [64,64]
    const float* __restrict__ W_dst,      // [64,64]
    const float* __restrict__ Wg,         // [128,64]
    const float* __restrict__ te,         // [50,64]
    const float* __restrict__ tek,        // [50,64]
    const int* __restrict__ nbr,          // [N,50]
    const int* __restrict__ timev,        // [N,50]
    float* __restrict__ out)              // [N,64]
{
    __shared__ unsigned int ws32[64 * 33];
    __shared__ unsigned int te32[L * 33];
    __shared__ unsigned int mbs[4][L * 33];

    const int tid = threadIdx.x, lane = tid & 63, wid = tid >> 6;
    const int n = blockIdx.x * 4 + wid;

    // ---- stage W_src and te as packed bf16 ----
    {
        const float2* Wf2 = (const float2*)W_src;
        const float2* Te2 = (const float2*)te;
        for (int idx = tid; idx < 2048; idx += 256) {
            float2 w = Wf2[idx];
            ws32[(idx >> 5) * 33 + (idx & 31)] = packbf(w.x, w.y);
            if (idx < 1600) {
                float2 t2 = Te2[idx];
                te32[(idx >> 5) * 33 + (idx & 31)] = packbf(t2.x, t2.y);
            }
        }
    }
    __syncthreads();

    // ---- neighborhood metadata ----
    int t  = (lane < L) ? timev[(size_t)n * L + lane] : 0;
    int nb = (lane < L) ? nbr[(size_t)n * L + lane]  : 0;
    unsigned int key  = (lane < L) ? ((((unsigned)t) << 6) | (unsigned)lane) : 0u;
    unsigned int key2 = (lane < L) ? ((((unsigned)t) << 6) | (unsigned)(63 - lane)) : 0u;

    int rank = 0;                       // stable ascending rank = argsort(argsort)
#pragma unroll
    for (int j = 0; j < L; j++) {
        unsigned int kj = (unsigned int)rli((int)key, j);   // SGPR compare operand
        rank += (kj < key) ? 1 : 0;
    }
    int re_o = (lane < L) ? (L - 1 - rank) : 0;

    unsigned int m2 = key2;             // first argmax(time)
#pragma unroll
    for (int s = 32; s; s >>= 1) { unsigned int o2 = __shfl_xor(m2, s); m2 = (o2 > m2) ? o2 : m2; }
    const int last = 63 - (int)(m2 & 63u);
    const int rr = (lane < L) ? lane : (L - 1);

    // ---- dh = W_dst^T f  (lanes = d) ----
    float f = dst_feat[(size_t)n * D + lane];
    float dh;
    {
        float b0 = 0.f, b1 = 0.f, b2 = 0.f, b3 = 0.f;
#pragma unroll
        for (int k = 0; k < 64; k += 4) {
            b0 += rl(f, k + 0) * W_dst[(k + 0) * 64 + lane];
            b1 += rl(f, k + 1) * W_dst[(k + 1) * 64 + lane];
            b2 += rl(f, k + 2) * W_dst[(k + 2) * 64 + lane];
            b3 += rl(f, k + 3) * W_dst[(k + 3) * 64 + lane];
        }
        dh = (b0 + b1) + (b2 + b3);
    }

    // ---- v1 = W_src dh  (lanes = k), packed rows from LDS ----
    float v1;
    {
        float b0 = 0.f, b1 = 0.f, b2 = 0.f, b3 = 0.f;
#pragma unroll
        for (int j = 0; j < 32; j += 2) {
            unsigned int u0 = ws32[lane * 33 + j];
            unsigned int u1 = ws32[lane * 33 + j + 1];
            b0 += lof(u0) * rl(dh, 2 * j + 0);
            b1 += hif(u0) * rl(dh, 2 * j + 1);
            b2 += lof(u1) * rl(dh, 2 * j + 2);
            b3 += hif(u1) * rl(dh, 2 * j + 3);
        }
        v1 = (b0 + b1) + (b2 + b3);
    }

    // ---- gather mailbox (2 rows/iter: half-wave per row), bf16-pack ----
    unsigned int* mbw = mbs[wid];
    {
        const float2* src2 = (const float2*)src_feat;
        int half = lane >> 5, col = lane & 31;
#pragma unroll
        for (int l = 0; l < L; l += 2) {
            int ra = rli(nb, l), rb = rli(nb, l + 1);    // SGPRs
            int r = half ? rb : ra;
            float2 v = src2[(size_t)r * 32 + col];
            mbw[(l + half) * 33 + col] = packbf(v.x, v.y);
        }
    }
    __syncthreads();

    // ---- raw_last (lanes = d) ----
    unsigned int ul = mbw[last * 33 + (lane >> 1)];
    float rlast = (lane & 1) ? hif(ul) : lof(ul);

    // ---- g = W_src^T raw_last  (lanes = d) ----
    float g;
    {
        float b0 = 0.f, b1 = 0.f, b2 = 0.f, b3 = 0.f;
#pragma unroll
        for (int k = 0; k < 64; k += 4) {
            b0 += rl(rlast, k + 0) * W_src[(k + 0) * 64 + lane];
            b1 += rl(rlast, k + 1) * W_src[(k + 1) * 64 + lane];
            b2 += rl(rlast, k + 2) * W_src[(k + 2) * 64 + lane];
            b3 += rl(rlast, k + 3) * W_src[(k + 3) * 64 + lane];
        }
        g = (b0 + b1) + (b2 + b3);
    }

    // ---- v2 = W_src g  (lanes = k) ----
    float v2;
    {
        float b0 = 0.f, b1 = 0.f, b2 = 0.f, b3 = 0.f;
#pragma unroll
        for (int j = 0; j < 32; j += 2) {
            unsigned int u0 = ws32[lane * 33 + j];
            unsigned int u1 = ws32[lane * 33 + j + 1];
            b0 += lof(u0) * rl(g, 2 * j + 0);
            b1 += hif(u0) * rl(g, 2 * j + 1);
            b2 += lof(u1) * rl(g, 2 * j + 2);
            b3 += hif(u1) * rl(g, 2 * j + 3);
        }
        v2 = (b0 + b1) + (b2 + b3);
    }

    // ---- teh[r] = te[r].dh  (lanes = rank), te from LDS ----
    float teh;
    {
        float b0 = 0.f, b1 = 0.f, b2 = 0.f, b3 = 0.f;
#pragma unroll
        for (int j = 0; j < 32; j += 2) {
            unsigned int u0 = te32[rr * 33 + j];
            unsigned int u1 = te32[rr * 33 + j + 1];
            b0 += lof(u0) * rl(dh, 2 * j + 0);
            b1 += hif(u0) * rl(dh, 2 * j + 1);
            b2 += lof(u1) * rl(dh, 2 * j + 2);
            b3 += hif(u1) * rl(dh, 2 * j + 3);
        }
        teh = (b0 + b1) + (b2 + b3);
    }

    // ---- scores e, e1  (lanes = neighbor) ----
    float e, e1;
    {
        float ea = 0.f, eb = 0.f, qa = 0.f, qb = 0.f;
#pragma unroll
        for (int j = 0; j < 32; j += 2) {
            unsigned int u0 = mbw[rr * 33 + j];
            unsigned int u1 = mbw[rr * 33 + j + 1];
            float m0 = lof(u0), m1 = hif(u0), m2f = lof(u1), m3 = hif(u1);
            ea += m0 * rl(v1, 2 * j + 0) + m1 * rl(v1, 2 * j + 1);
            eb += m2f * rl(v1, 2 * j + 2) + m3 * rl(v1, 2 * j + 3);
            qa += m0 * rl(v2, 2 * j + 0) + m1 * rl(v2, 2 * j + 1);
            qb += m2f * rl(v2, 2 * j + 2) + m3 * rl(v2, 2 * j + 3);
        }
        e = ea + eb; e1 = qa + qb;
    }
    e = (e + __shfl(teh, re_o)) * 0.125f;   // per-lane index: keep bpermute (1 op)
    e1 *= 0.125f;
    if (lane >= L) { e = -3e38f; e1 = -3e38f; }

    // ---- dual softmax over neighbors ----
    float mx = e;
#pragma unroll
    for (int s = 32; s; s >>= 1) { float o2 = __shfl_xor(mx, s); mx = (o2 > mx) ? o2 : mx; }
    float ex = __expf(e - mx);
    float sm = ex;
#pragma unroll
    for (int s = 32; s; s >>= 1) sm += __shfl_xor(sm, s);
    float alpha = ex / sm;

    float mx1 = e1;
#pragma unroll
    for (int s = 32; s; s >>= 1) { float o2 = __shfl_xor(mx1, s); mx1 = (o2 > mx1) ? o2 : mx1; }
    float ex1 = __expf(e1 - mx1);
    float sm1 = ex1;
#pragma unroll
    for (int s = 32; s; s >>= 1) sm1 += __shfl_xor(sm1, s);
    float aw = ex1 / sm1;

    // ---- weighted sums over rows (lanes = d) ----
    float sl, ss, tacc;
    {
        float sA = 0.f, sB = 0.f, hA = 0.f, hB = 0.f, tA = 0.f, tB = 0.f;
        int hcol = lane >> 1, odd = lane & 1;
#pragma unroll
        for (int l = 0; l < L; l += 2) {
            float saA = rl(alpha, l),     s1A = rl(aw, l);
            float saB = rl(alpha, l + 1), s1B = rl(aw, l + 1);
            int   roA = rli(re_o, l),     roB = rli(re_o, l + 1);   // SGPR row bases
            unsigned int uA = mbw[(l + 0) * 33 + hcol];
            unsigned int uB = mbw[(l + 1) * 33 + hcol];
            float mA = odd ? hif(uA) : lof(uA);
            float mB = odd ? hif(uB) : lof(uB);
            sA += saA * mA; hA += s1A * mA; tA += saA * tek[roA * 64 + lane];
            sB += saB * mB; hB += s1B * mB; tB += saB * tek[roB * 64 + lane];
        }
        sl = sA + sB; ss = hA + hB; tacc = tA + tB;
    }

    // ---- hl/hs = W_src^T sl/ss  (lanes = d) ----
    float hl, hs;
    {
        float lA = 0.f, lB = 0.f, sA = 0.f, sB = 0.f;
#pragma unroll
        for (int k = 0; k < 64; k += 2) {
            float w0 = W_src[(k + 0) * 64 + lane];
            float w1 = W_src[(k + 1) * 64 + lane];
            lA += rl(sl, k + 0) * w0; sA += rl(ss, k + 0) * w0;
            lB += rl(sl, k + 1) * w1; sB += rl(ss, k + 1) * w1;
        }
        hl = tacc + lA + lB; hs = sA + sB;
    }

    // ---- out = elu([hl|hs] @ Wg + f) ----
    float o;
    {
        float o0 = 0.f, o1 = 0.f, o2 = 0.f, o3 = 0.f;
#pragma unroll
        for (int k = 0; k < 64; k += 2) {
            o0 += rl(hl, k + 0) * Wg[(k + 0) * 64 + lane];
            o1 += rl(hl, k + 1) * Wg[(k + 1) * 64 + lane];
            o2 += rl(hs, k + 0) * Wg[(k + 64) * 64 + lane];
            o3 += rl(hs, k + 1) * Wg[(k + 65) * 64 + lane];
        }
        o = f + (o0 + o1) + (o2 + o3);
    }
    o = (o > 0.f) ? o : (__expf(o) - 1.f);
    out[(size_t)n * D + lane] = o;
}

extern "C" void kernel_launch(void* const* d_in, const int* in_sizes, int n_in,
                              void* d_out, int out_size, void* d_ws, size_t ws_size,
                              hipStream_t stream) {
    const float* user_feat = (const float*)d_in[0];
    const float* item_feat = (const float*)d_in[1];
    const float* W_u  = (const float*)d_in[2];
    const float* W_i  = (const float*)d_in[3];
    const float* Wg_u = (const float*)d_in[4];
    const float* Wg_i = (const float*)d_in[5];
    const float* i_te   = (const float*)d_in[6];
    const float* i_te_k = (const float*)d_in[7];
    const float* u_te   = (const float*)d_in[8];
    const float* u_te_k = (const float*)d_in[9];
    const int* item_nbr  = (const int*)d_in[10];
    const int* item_time = (const int*)d_in[11];
    const int* user_nbr  = (const int*)d_in[12];
    const int* user_time = (const int*)d_in[13];
    (void)in_sizes; (void)n_in; (void)out_size; (void)d_ws; (void)ws_size;

    float* outp = (float*)d_out;   // user_out then item_out

    // item side: mailbox = user rows (W_u), dst = items (W_i)
    attn_f32<<<NUM_I / 4, 256, 0, stream>>>(
        user_feat, item_feat, W_u, W_i, Wg_i, i_te, i_te_k,
        item_nbr, item_time, outp + (size_t)NUM_U * D);
    // user side: mailbox = item rows (W_i), dst = users (W_u)
    attn_f32<<<NUM_U / 4, 256, 0, stream>>>(
        item_feat, user_feat, W_i, W_u, Wg_u, u_te, u_te_k,
        user_nbr, user_time, outp);
}

// Round 6
// 277.481 us; speedup vs baseline: 2.6185x; 1.6119x over previous
//
#include <hip/hip_runtime.h>
#include <stdint.h>

#define D   64
#define L   50
#define NUM_U 30000
#define NUM_I 20000

// Measured history: r3 float tensors are f32; r4 __shfl=ds_bpermute was the
// bottleneck; r5 readlane->SGPR broadcasts: VALUBusy 25->63%, 447us, now
// VALU-issue-bound. r6: precompute H=feat@W into ws (packed bf16) -- kills the
// four per-node 64-deep matvecs (~900 instr/wave) and halves gather traffic.

__device__ __forceinline__ float lof(unsigned int u) {
    union { unsigned int i; float f; } v; v.i = u << 16; return v.f;
}
__device__ __forceinline__ float hif(unsigned int u) {
    union { unsigned int i; float f; } v; v.i = u & 0xffff0000u; return v.f;
}
__device__ __forceinline__ unsigned int f2bfbits(float f) {
    union { float f; unsigned int i; } v; v.f = f;
    return (v.i + 0x7fffu + ((v.i >> 16) & 1u)) >> 16;   // RNE
}
__device__ __forceinline__ unsigned int packbf(float a, float b) {
    return f2bfbits(a) | (f2bfbits(b) << 16);
}
__device__ __forceinline__ float rl(float v, int l) {
    return __int_as_float(__builtin_amdgcn_readlane(__float_as_int(v), l));
}
__device__ __forceinline__ int rli(int v, int l) {
    return __builtin_amdgcn_readlane(v, l);
}

// ---------------- K1: H = feat @ W, packed bf16 pairs (32 dw/row) ----------
// rows [0,NUM_U) = user_feat@W_u ; rows [NUM_U,50000) = item_feat@W_i
__global__ __launch_bounds__(256) void gemm_h(
    const float* __restrict__ user_feat,
    const float* __restrict__ item_feat,
    const float* __restrict__ W_u,
    const float* __restrict__ W_i,
    unsigned int* __restrict__ H)
{
    const int tid = threadIdx.x, lane = tid & 63, wid = tid >> 6;
    int r0 = blockIdx.x * 16 + wid * 4;           // 30000%16==0: no side straddle
    const float* src; const float* W;
    if (r0 < NUM_U) { src = user_feat + (size_t)r0 * D;            W = W_u; }
    else            { src = item_feat + (size_t)(r0 - NUM_U) * D;  W = W_i; }

    float f0 = src[0 * D + lane], f1 = src[1 * D + lane];
    float f2 = src[2 * D + lane], f3 = src[3 * D + lane];
    float a0 = 0.f, a1 = 0.f, a2 = 0.f, a3 = 0.f;
#pragma unroll
    for (int k = 0; k < 64; k++) {
        float wk = W[k * 64 + lane];
        a0 += rl(f0, k) * wk; a1 += rl(f1, k) * wk;
        a2 += rl(f2, k) * wk; a3 += rl(f3, k) * wk;
    }
    int li = (lane & 31) << 1;
    float p0 = __shfl(a0, li), q0 = __shfl(a0, li | 1);
    float p1 = __shfl(a1, li), q1 = __shfl(a1, li | 1);
    float p2 = __shfl(a2, li), q2 = __shfl(a2, li | 1);
    float p3 = __shfl(a3, li), q3 = __shfl(a3, li | 1);
    if (lane < 32) {
        H[(size_t)(r0 + 0) * 32 + lane] = packbf(p0, q0);
        H[(size_t)(r0 + 1) * 32 + lane] = packbf(p1, q1);
        H[(size_t)(r0 + 2) * 32 + lane] = packbf(p2, q2);
        H[(size_t)(r0 + 3) * 32 + lane] = packbf(p3, q3);
    }
}

// ---------------- K2: attention on projected mailboxes (one wave/node) ------
//   e_l = mbh_l.dh + teh[re_o_l] ; e1_l = mbh_last.mbh_l
//   h_long = sum a (mbh_l + tek[re_o_l]) ; h_short = sum a1 mbh_l
//   out = elu([h_long|h_short] @ Wg + f_dst)
__global__ __launch_bounds__(256) void attn_split(
    const unsigned int* __restrict__ H,
    int src_base, int dst_base,
    const float* __restrict__ dst_feat,
    const float* __restrict__ Wg,         // [128,64] f32
    const float* __restrict__ te,         // [50,64] f32
    const float* __restrict__ tek,        // [50,64] f32
    const int* __restrict__ nbr,          // [N,50]
    const int* __restrict__ timev,        // [N,50]
    float* __restrict__ out)              // [N,64]
{
    __shared__ unsigned int te32[L * 33];     // packed bf16, stride 33 (2-way alias max)
    __shared__ unsigned int mbs[4][L * 33];

    const int tid = threadIdx.x, lane = tid & 63, wid = tid >> 6;
    const int n = blockIdx.x * 4 + wid;

    {   // stage te packed
        const float2* Te2 = (const float2*)te;
        for (int p = tid; p < 1600; p += 256) {
            float2 t2 = Te2[p];
            te32[(p >> 5) * 33 + (p & 31)] = packbf(t2.x, t2.y);
        }
    }
    __syncthreads();

    // ---- neighborhood metadata ----
    int t  = (lane < L) ? timev[(size_t)n * L + lane] : 0;
    int nb = (lane < L) ? nbr[(size_t)n * L + lane]  : 0;
    unsigned int key  = (lane < L) ? ((((unsigned)t) << 6) | (unsigned)lane) : 0u;
    unsigned int key2 = (lane < L) ? ((((unsigned)t) << 6) | (unsigned)(63 - lane)) : 0u;

    int rank = 0;                       // stable ascending rank = argsort(argsort)
#pragma unroll
    for (int j = 0; j < L; j++) {
        unsigned int kj = (unsigned int)rli((int)key, j);
        rank += (kj < key) ? 1 : 0;
    }
    int re_o = (lane < L) ? (L - 1 - rank) : 0;

    unsigned int m2 = key2;             // first argmax(time)
#pragma unroll
    for (int s = 32; s; s >>= 1) { unsigned int o2 = __shfl_xor(m2, s); m2 = (o2 > m2) ? o2 : m2; }
    const int last = 63 - (int)(m2 & 63u);
    const int rr = (lane < L) ? lane : (L - 1);

    // ---- dh = projected dst row (lanes = d), from packed H ----
    unsigned int ud = H[(size_t)(dst_base + n) * 32 + (lane >> 1)];
    float dh = (lane & 1) ? hif(ud) : lof(ud);

    // ---- gather projected mailbox rows (2 rows/iter, half-wave each) ----
    unsigned int* mbw = mbs[wid];
    {
        const unsigned int* Hs = H + (size_t)src_base * 32;
        int half = lane >> 5, col = lane & 31;
#pragma unroll
        for (int l = 0; l < L; l += 2) {
            int ra = rli(nb, l), rb = rli(nb, l + 1);
            int r = half ? rb : ra;
            mbw[(l + half) * 33 + col] = Hs[(size_t)r * 32 + col];
        }
    }
    __syncthreads();

    // ---- mbh_last (lanes = d) ----
    unsigned int ulm = mbw[last * 33 + (lane >> 1)];
    float lm = (lane & 1) ? hif(ulm) : lof(ulm);

    // ---- teh[r] = te[r].dh (lanes = rank) ----
    float teh;
    {
        float b0 = 0.f, b1 = 0.f, b2 = 0.f, b3 = 0.f;
#pragma unroll
        for (int j = 0; j < 32; j += 2) {
            unsigned int u0 = te32[rr * 33 + j];
            unsigned int u1 = te32[rr * 33 + j + 1];
            b0 += lof(u0) * rl(dh, 2 * j + 0);
            b1 += hif(u0) * rl(dh, 2 * j + 1);
            b2 += lof(u1) * rl(dh, 2 * j + 2);
            b3 += hif(u1) * rl(dh, 2 * j + 3);
        }
        teh = (b0 + b1) + (b2 + b3);
    }

    // ---- scores e, e1 (lanes = neighbor) ----
    float e, e1;
    {
        float ea = 0.f, eb = 0.f, qa = 0.f, qb = 0.f;
#pragma unroll
        for (int j = 0; j < 32; j += 2) {
            unsigned int u0 = mbw[rr * 33 + j];
            unsigned int u1 = mbw[rr * 33 + j + 1];
            float m0 = lof(u0), m1 = hif(u0), m2f = lof(u1), m3 = hif(u1);
            ea += m0 * rl(dh, 2 * j + 0) + m1 * rl(dh, 2 * j + 1);
            eb += m2f * rl(dh, 2 * j + 2) + m3 * rl(dh, 2 * j + 3);
            qa += m0 * rl(lm, 2 * j + 0) + m1 * rl(lm, 2 * j + 1);
            qb += m2f * rl(lm, 2 * j + 2) + m3 * rl(lm, 2 * j + 3);
        }
        e = ea + eb; e1 = qa + qb;
    }
    e = (e + __shfl(teh, re_o)) * 0.125f;   // per-lane index: single bpermute
    e1 *= 0.125f;
    if (lane >= L) { e = -3e38f; e1 = -3e38f; }

    // ---- dual softmax over neighbors ----
    float mx = e;
#pragma unroll
    for (int s = 32; s; s >>= 1) { float o2 = __shfl_xor(mx, s); mx = (o2 > mx) ? o2 : mx; }
    float ex = __expf(e - mx);
    float sm = ex;
#pragma unroll
    for (int s = 32; s; s >>= 1) sm += __shfl_xor(sm, s);
    float alpha = ex / sm;

    float mx1 = e1;
#pragma unroll
    for (int s = 32; s; s >>= 1) { float o2 = __shfl_xor(mx1, s); mx1 = (o2 > mx1) ? o2 : mx1; }
    float ex1 = __expf(e1 - mx1);
    float sm1 = ex1;
#pragma unroll
    for (int s = 32; s; s >>= 1) sm1 += __shfl_xor(sm1, s);
    float aw = ex1 / sm1;

    // ---- weighted sums (lanes = d); tek f32 global (coalesced, L1) ----
    float hl, hs;
    {
        float sA = 0.f, sB = 0.f, hA = 0.f, hB = 0.f, tA = 0.f, tB = 0.f;
        int hcol = lane >> 1, odd = lane & 1;
#pragma unroll
        for (int l = 0; l < L; l += 2) {
            float saA = rl(alpha, l),     s1A = rl(aw, l);
            float saB = rl(alpha, l + 1), s1B = rl(aw, l + 1);
            int   roA = rli(re_o, l),     roB = rli(re_o, l + 1);
            unsigned int uA = mbw[(l + 0) * 33 + hcol];
            unsigned int uB = mbw[(l + 1) * 33 + hcol];
            float mA = odd ? hif(uA) : lof(uA);
            float mB = odd ? hif(uB) : lof(uB);
            sA += saA * mA; hA += s1A * mA; tA += saA * tek[roA * 64 + lane];
            sB += saB * mB; hB += s1B * mB; tB += saB * tek[roB * 64 + lane];
        }
        hl = (sA + sB) + (tA + tB);   // h_long (projection already applied)
        hs = hA + hB;                 // h_short
    }

    // ---- out = elu([hl|hs] @ Wg + f) ----
    float f = dst_feat[(size_t)n * D + lane];
    float o;
    {
        float o0 = 0.f, o1 = 0.f, o2 = 0.f, o3 = 0.f;
#pragma unroll
        for (int k = 0; k < 64; k += 2) {
            o0 += rl(hl, k + 0) * Wg[(k + 0) * 64 + lane];
            o1 += rl(hl, k + 1) * Wg[(k + 1) * 64 + lane];
            o2 += rl(hs, k + 0) * Wg[(k + 64) * 64 + lane];
            o3 += rl(hs, k + 1) * Wg[(k + 65) * 64 + lane];
        }
        o = f + (o0 + o1) + (o2 + o3);
    }
    o = (o > 0.f) ? o : (__expf(o) - 1.f);
    out[(size_t)n * D + lane] = o;
}

// ---------------- fallback: round-5 monolith (passed, 447us) ---------------
__global__ __launch_bounds__(256) void attn_mono(
    const float* __restrict__ src_feat, const float* __restrict__ dst_feat,
    const float* __restrict__ W_src, const float* __restrict__ W_dst,
    const float* __restrict__ Wg, const float* __restrict__ te,
    const float* __restrict__ tek, const int* __restrict__ nbr,
    const int* __restrict__ timev, float* __restrict__ out)
{
    __shared__ unsigned int ws32[64 * 33];
    __shared__ unsigned int te32[L * 33];
    __shared__ unsigned int mbs[4][L * 33];
    const int tid = threadIdx.x, lane = tid & 63, wid = tid >> 6;
    const int n = blockIdx.x * 4 + wid;
    {
        const float2* Wf2 = (const float2*)W_src;
        const float2* Te2 = (const float2*)te;
        for (int idx = tid; idx < 2048; idx += 256) {
            float2 w = Wf2[idx];
            ws32[(idx >> 5) * 33 + (idx & 31)] = packbf(w.x, w.y);
            if (idx < 1600) {
                float2 t2 = Te2[idx];
                te32[(idx >> 5) * 33 + (idx & 31)] = packbf(t2.x, t2.y);
            }
        }
    }
    __syncthreads();
    int t  = (lane < L) ? timev[(size_t)n * L + lane] : 0;
    int nb = (lane < L) ? nbr[(size_t)n * L + lane]  : 0;
    unsigned int key  = (lane < L) ? ((((unsigned)t) << 6) | (unsigned)lane) : 0u;
    unsigned int key2 = (lane < L) ? ((((unsigned)t) << 6) | (unsigned)(63 - lane)) : 0u;
    int rank = 0;
#pragma unroll
    for (int j = 0; j < L; j++) {
        unsigned int kj = (unsigned int)rli((int)key, j);
        rank += (kj < key) ? 1 : 0;
    }
    int re_o = (lane < L) ? (L - 1 - rank) : 0;
    unsigned int m2 = key2;
#pragma unroll
    for (int s = 32; s; s >>= 1) { unsigned int o2 = __shfl_xor(m2, s); m2 = (o2 > m2) ? o2 : m2; }
    const int last = 63 - (int)(m2 & 63u);
    const int rr = (lane < L) ? lane : (L - 1);
    float f = dst_feat[(size_t)n * D + lane];
    float dh;
    {
        float b0 = 0.f, b1 = 0.f, b2 = 0.f, b3 = 0.f;
#pragma unroll
        for (int k = 0; k < 64; k += 4) {
            b0 += rl(f, k + 0) * W_dst[(k + 0) * 64 + lane];
            b1 += rl(f, k + 1) * W_dst[(k + 1) * 64 + lane];
            b2 += rl(f, k + 2) * W_dst[(k + 2) * 64 + lane];
            b3 += rl(f, k + 3) * W_dst[(k + 3) * 64 + lane];
        }
        dh = (b0 + b1) + (b2 + b3);
    }
    float v1;
    {
        float b0 = 0.f, b1 = 0.f, b2 = 0.f, b3 = 0.f;
#pragma unroll
        for (int j = 0; j < 32; j += 2) {
            unsigned int u0 = ws32[lane * 33 + j];
            unsigned int u1 = ws32[lane * 33 + j + 1];
            b0 += lof(u0) * rl(dh, 2 * j + 0);
            b1 += hif(u0) * rl(dh, 2 * j + 1);
            b2 += lof(u1) * rl(dh, 2 * j + 2);
            b3 += hif(u1) * rl(dh, 2 * j + 3);
        }
        v1 = (b0 + b1) + (b2 + b3);
    }
    unsigned int* mbw = mbs[wid];
    {
        const float2* src2 = (const float2*)src_feat;
        int half = lane >> 5, col = lane & 31;
#pragma unroll
        for (int l = 0; l < L; l += 2) {
            int ra = rli(nb, l), rb = rli(nb, l + 1);
            int r = half ? rb : ra;
            float2 v = src2[(size_t)r * 32 + col];
            mbw[(l + half) * 33 + col] = packbf(v.x, v.y);
        }
    }
    __syncthreads();
    unsigned int ul = mbw[last * 33 + (lane >> 1)];
    float rlast = (lane & 1) ? hif(ul) : lof(ul);
    float g;
    {
        float b0 = 0.f, b1 = 0.f, b2 = 0.f, b3 = 0.f;
#pragma unroll
        for (int k = 0; k < 64; k += 4) {
            b0 += rl(rlast, k + 0) * W_src[(k + 0) * 64 + lane];
            b1 += rl(rlast, k + 1) * W_src[(k + 1) * 64 + lane];
            b2 += rl(rlast, k + 2) * W_src[(k + 2) * 64 + lane];
            b3 += rl(rlast, k + 3) * W_src[(k + 3) * 64 + lane];
        }
        g = (b0 + b1) + (b2 + b3);
    }
    float v2;
    {
        float b0 = 0.f, b1 = 0.f, b2 = 0.f, b3 = 0.f;
#pragma unroll
        for (int j = 0; j < 32; j += 2) {
            unsigned int u0 = ws32[lane * 33 + j];
            unsigned int u1 = ws32[lane * 33 + j + 1];
            b0 += lof(u0) * rl(g, 2 * j + 0);
            b1 += hif(u0) * rl(g, 2 * j + 1);
            b2 += lof(u1) * rl(g, 2 * j + 2);
            b3 += hif(u1) * rl(g, 2 * j + 3);
        }
        v2 = (b0 + b1) + (b2 + b3);
    }
    float teh;
    {
        float b0 = 0.f, b1 = 0.f, b2 = 0.f, b3 = 0.f;
#pragma unroll
        for (int j = 0; j < 32; j += 2) {
            unsigned int u0 = te32[rr * 33 + j];
            unsigned int u1 = te32[rr * 33 + j + 1];
            b0 += lof(u0) * rl(dh, 2 * j + 0);
            b1 += hif(u0) * rl(dh, 2 * j + 1);
            b2 += lof(u1) * rl(dh, 2 * j + 2);
            b3 += hif(u1) * rl(dh, 2 * j + 3);
        }
        teh = (b0 + b1) + (b2 + b3);
    }
    float e, e1;
    {
        float ea = 0.f, eb = 0.f, qa = 0.f, qb = 0.f;
#pragma unroll
        for (int j = 0; j < 32; j += 2) {
            unsigned int u0 = mbw[rr * 33 + j];
            unsigned int u1 = mbw[rr * 33 + j + 1];
            float m0 = lof(u0), m1 = hif(u0), m2f = lof(u1), m3 = hif(u1);
            ea += m0 * rl(v1, 2 * j + 0) + m1 * rl(v1, 2 * j + 1);
            eb += m2f * rl(v1, 2 * j + 2) + m3 * rl(v1, 2 * j + 3);
            qa += m0 * rl(v2, 2 * j + 0) + m1 * rl(v2, 2 * j + 1);
            qb += m2f * rl(v2, 2 * j + 2) + m3 * rl(v2, 2 * j + 3);
        }
        e = ea + eb; e1 = qa + qb;
    }
    e = (e + __shfl(teh, re_o)) * 0.125f;
    e1 *= 0.125f;
    if (lane >= L) { e = -3e38f; e1 = -3e38f; }
    float mx = e;
#pragma unroll
    for (int s = 32; s; s >>= 1) { float o2 = __shfl_xor(mx, s); mx = (o2 > mx) ? o2 : mx; }
    float ex = __expf(e - mx);
    float sm = ex;
#pragma unroll
    for (int s = 32; s; s >>= 1) sm += __shfl_xor(sm, s);
    float alpha = ex / sm;
    float mx1 = e1;
#pragma unroll
    for (int s = 32; s; s >>= 1) { float o2 = __shfl_xor(mx1, s); mx1 = (o2 > mx1) ? o2 : mx1; }
    float ex1 = __expf(e1 - mx1);
    float sm1 = ex1;
#pragma unroll
    for (int s = 32; s; s >>= 1) sm1 += __shfl_xor(sm1, s);
    float aw = ex1 / sm1;
    float sl, ss, tacc;
    {
        float sA = 0.f, sB = 0.f, hA = 0.f, hB = 0.f, tA = 0.f, tB = 0.f;
        int hcol = lane >> 1, odd = lane & 1;
#pragma unroll
        for (int l = 0; l < L; l += 2) {
            float saA = rl(alpha, l),     s1A = rl(aw, l);
            float saB = rl(alpha, l + 1), s1B = rl(aw, l + 1);
            int   roA = rli(re_o, l),     roB = rli(re_o, l + 1);
            unsigned int uA = mbw[(l + 0) * 33 + hcol];
            unsigned int uB = mbw[(l + 1) * 33 + hcol];
            float mA = odd ? hif(uA) : lof(uA);
            float mB = odd ? hif(uB) : lof(uB);
            sA += saA * mA; hA += s1A * mA; tA += saA * tek[roA * 64 + lane];
            sB += saB * mB; hB += s1B * mB; tB += saB * tek[roB * 64 + lane];
        }
        sl = sA + sB; ss = hA + hB; tacc = tA + tB;
    }
    float hl, hs;
    {
        float lA = 0.f, lB = 0.f, sA = 0.f, sB = 0.f;
#pragma unroll
        for (int k = 0; k < 64; k += 2) {
            float w0 = W_src[(k + 0) * 64 + lane];
            float w1 = W_src[(k + 1) * 64 + lane];
            lA += rl(sl, k + 0) * w0; sA += rl(ss, k + 0) * w0;
            lB += rl(sl, k + 1) * w1; sB += rl(ss, k + 1) * w1;
        }
        hl = tacc + lA + lB; hs = sA + sB;
    }
    float o;
    {
        float o0 = 0.f, o1 = 0.f, o2 = 0.f, o3 = 0.f;
#pragma unroll
        for (int k = 0; k < 64; k += 2) {
            o0 += rl(hl, k + 0) * Wg[(k + 0) * 64 + lane];
            o1 += rl(hl, k + 1) * Wg[(k + 1) * 64 + lane];
            o2 += rl(hs, k + 0) * Wg[(k + 64) * 64 + lane];
            o3 += rl(hs, k + 1) * Wg[(k + 65) * 64 + lane];
        }
        o = f + (o0 + o1) + (o2 + o3);
    }
    o = (o > 0.f) ? o : (__expf(o) - 1.f);
    out[(size_t)n * D + lane] = o;
}

extern "C" void kernel_launch(void* const* d_in, const int* in_sizes, int n_in,
                              void* d_out, int out_size, void* d_ws, size_t ws_size,
                              hipStream_t stream) {
    const float* user_feat = (const float*)d_in[0];
    const float* item_feat = (const float*)d_in[1];
    const float* W_u  = (const float*)d_in[2];
    const float* W_i  = (const float*)d_in[3];
    const float* Wg_u = (const float*)d_in[4];
    const float* Wg_i = (const float*)d_in[5];
    const float* i_te   = (const float*)d_in[6];
    const float* i_te_k = (const float*)d_in[7];
    const float* u_te   = (const float*)d_in[8];
    const float* u_te_k = (const float*)d_in[9];
    const int* item_nbr  = (const int*)d_in[10];
    const int* item_time = (const int*)d_in[11];
    const int* user_nbr  = (const int*)d_in[12];
    const int* user_time = (const int*)d_in[13];
    (void)in_sizes; (void)n_in; (void)out_size;

    float* outp = (float*)d_out;   // user_out then item_out
    const size_t H_BYTES = (size_t)(NUM_U + NUM_I) * 32 * 4;   // 6.4 MB

    if (ws_size >= H_BYTES) {
        unsigned int* H = (unsigned int*)d_ws;   // packed bf16, users then items
        gemm_h<<<(NUM_U + NUM_I) / 16, 256, 0, stream>>>(
            user_feat, item_feat, W_u, W_i, H);
        // item side: mailbox = H user rows, dst = H item rows
        attn_split<<<NUM_I / 4, 256, 0, stream>>>(
            H, 0, NUM_U, item_feat, Wg_i, i_te, i_te_k,
            item_nbr, item_time, outp + (size_t)NUM_U * D);
        // user side: mailbox = H item rows, dst = H user rows
        attn_split<<<NUM_U / 4, 256, 0, stream>>>(
            H, NUM_U, 0, user_feat, Wg_u, u_te, u_te_k,
            user_nbr, user_time, outp);
    } else {
        attn_mono<<<NUM_I / 4, 256, 0, stream>>>(
            user_feat, item_feat, W_u, W_i, Wg_i, i_te, i_te_k,
            item_nbr, item_time, outp + (size_t)NUM_U * D);
        attn_mono<<<NUM_U / 4, 256, 0, stream>>>(
            item_feat, user_feat, W_i, W_u, Wg_u, u_te, u_te_k,
            user_nbr, user_time, outp);
    }
}